// Round 11
// baseline (193.842 us; speedup 1.0000x reference)
//
#include <hip/hip_runtime.h>
#include <hip/hip_bf16.h>

// GCN 2-layer, 6 launches. Buckets of 128 nodes (391 buckets).
//   p1    : bucket histogram (dst only) + W1/W2 transpose->bf16
//   p2a   : scan of per-partition bucket counts
//   p3    : partition edges into bucket-contiguous ebuf + edge_index copy-out
//   p4    : per-bucket counting sort -> csr(ushort), rowptr, dis
//           + fused xconv: Xhs = bf16(dis*X) [N][96] for the bucket's nodes
//   fused1: per 16-node block: gather rows -> LDS, then MFMA GEMM (K=96)
//           g2h = bf16( relu(d*(agg@W1t) + b1) * d )   [N][128]
//   fused2: same structure (K=128), out = relu( d*(agg@W2t) + b2 ) fp32
// 16 nodes/block (grid N/16=3125) => full occupancy during gather.
// All row operands bf16 (fp32 accumulation). Requires N < 65536.

#define HID 128
#define KIN 89
#define KP1 96    // layer-1 row: 96 bf16 = 192B = exactly 3 cache lines
#define KP2 128   // layer-2 row: 128 bf16 = 256B
#define BSH 7     // bucket = 128 nodes
#define BNODES 128
#define MAXBUCK 512   // capacity of bucket-indexed LDS/scan arrays
#define NPB 128       // partition blocks
#define P4CAP 3072    // staging capacity per bucket (mean ~2046, 5sd ~2270)

typedef __attribute__((ext_vector_type(8))) short bf16x8;
typedef __attribute__((ext_vector_type(4))) float f32x4;

static __device__ inline float2 unpack_bf16(unsigned v) {
    union { unsigned u; float f; } lo, hi;
    lo.u = v << 16;
    hi.u = v & 0xFFFF0000u;
    return make_float2(lo.f, hi.f);
}

static __device__ inline unsigned pack_bf16(float a, float b) {
    __hip_bfloat162 h = __float22bfloat162_rn(make_float2(a, b));
    return *reinterpret_cast<unsigned*>(&h);
}

static __device__ inline unsigned short f2bf(float v) {
    __hip_bfloat16 h = __float2bfloat16(v);
    return *reinterpret_cast<unsigned short*>(&h);
}

// ---- p1: histogram (dst only) + weight transposes ----
__global__ __launch_bounds__(256) void p1_kernel(
    const int* __restrict__ ei,
    int* __restrict__ histG,
    const float* __restrict__ W1, unsigned short* __restrict__ W1t,
    const float* __restrict__ W2, unsigned short* __restrict__ W2t,
    int E, int nbuck)
{
    __shared__ int h[MAXBUCK];
    const int tid = threadIdx.x, blk = blockIdx.x;
    const int* dst = ei + E;
    for (int b = tid; b < nbuck; b += 256) h[b] = 0;

    // weight transposes spread over the grid's first 28672 threads
    int tg = blk * 256 + tid;
    if (tg < HID * KP1) {
        int n = tg / KP1, k = tg % KP1;
        W1t[tg] = f2bf(k < KIN ? W1[(size_t)k * HID + n] : 0.0f);
    } else {
        int t2 = tg - HID * KP1;
        if (t2 < HID * HID) {
            int n = t2 / HID, k = t2 % HID;
            W2t[t2] = f2bf(W2[(size_t)k * HID + n]);
        }
    }
    __syncthreads();

    const int chunk = (E + NPB - 1) / NPB;
    const int beg = blk * chunk, end = min(beg + chunk, E);
    for (int i = beg + tid; i < end; i += 256)
        atomicAdd(&h[dst[i] >> BSH], 1);
    __syncthreads();
    for (int b = tid; b < nbuck; b += 256) histG[b * NPB + blk] = h[b];
}

// ---- p2a: per-bucket exclusive scan of its NPB counts + totals ----
__global__ __launch_bounds__(NPB) void p2a_kernel(
    int* __restrict__ histG, int* __restrict__ totals)
{
    __shared__ int wsum[NPB / 64];
    const int b = blockIdx.x, tid = threadIdx.x, lane = tid & 63, wid = tid >> 6;
    int c = histG[b * NPB + tid];
    int s = c;
#pragma unroll
    for (int off = 1; off < 64; off <<= 1) {
        int t = __shfl_up(s, off, 64);
        if (lane >= off) s += t;
    }
    if (lane == 63) wsum[wid] = s;
    __syncthreads();
    if (tid == 0) {
        int a = 0;
#pragma unroll
        for (int w = 0; w < NPB / 64; ++w) { int t = wsum[w]; wsum[w] = a; a += t; }
    }
    __syncthreads();
    int excl = wsum[wid] + s - c;
    histG[b * NPB + tid] = excl;
    if (tid == NPB - 1) totals[b] = excl + c;
}

// In-block exclusive scan of totals[0..nbuck), nbuck <= 512, 256 threads.
static __device__ inline void scan_totals2(const int* __restrict__ totals,
                                           int* __restrict__ sexcl,
                                           int* __restrict__ wsum,
                                           int nbuck, int tid)
{
    const int lane = tid & 63, wid = tid >> 6;
    const int i0 = 2 * tid, i1 = 2 * tid + 1;
    int t0 = (i0 < nbuck) ? totals[i0] : 0;
    int t1 = (i1 < nbuck) ? totals[i1] : 0;
    int p = t0 + t1;
    int s = p;
#pragma unroll
    for (int off = 1; off < 64; off <<= 1) {
        int t = __shfl_up(s, off, 64);
        if (lane >= off) s += t;
    }
    if (lane == 63) wsum[wid] = s;
    __syncthreads();
    if (tid == 0) {
        int a = 0;
#pragma unroll
        for (int w = 0; w < 4; ++w) { int t = wsum[w]; wsum[w] = a; a += t; }
    }
    __syncthreads();
    int excl = wsum[wid] + s - p;
    sexcl[i0] = excl;
    sexcl[i1] = excl + t0;
}

// ---- p3: partition edges into bucket-contiguous ebuf + edge copy-out ----
__global__ __launch_bounds__(256) void p3_part_kernel(
    const int* __restrict__ ei, const int* __restrict__ histG,
    const int* __restrict__ totals, unsigned* __restrict__ ebuf,
    float* __restrict__ outE,
    int E, int nbuck)
{
    __shared__ int cur[MAXBUCK];
    __shared__ int wsum[4];
    const int tid = threadIdx.x, blk = blockIdx.x;
    const int* src = ei;
    const int* dst = ei + E;
    scan_totals2(totals, cur, wsum, nbuck, tid);   // cur[b] = bucket base
    __syncthreads();
    for (int b = tid; b < nbuck; b += 256) cur[b] += histG[b * NPB + blk];
    const int chunk = (E + NPB - 1) / NPB;
    const int beg = blk * chunk, end = min(beg + chunk, E);
    __syncthreads();
    for (int i = beg + tid; i < end; i += 256) {
        int sxi = src[i];
        int d = dst[i];
        int b = d >> BSH;
        int pos = atomicAdd(&cur[b], 1);
        ebuf[pos] = ((unsigned)(d & (BNODES - 1)) << 16) | (unsigned)sxi;
        outE[i] = (float)sxi;
        outE[E + i] = (float)d;
    }
}

// ---- p4: per-bucket sort -> csr, rowptr, dis; then xconv for the bucket ----
__global__ __launch_bounds__(256) void p4_sort_kernel(
    const unsigned* __restrict__ ebuf, const int* __restrict__ totals,
    unsigned short* __restrict__ csr, int* __restrict__ rowptr,
    float* __restrict__ dis,
    const float* __restrict__ X, unsigned* __restrict__ Xhs,
    int N, int E, int nbuck)
{
    __shared__ int counts[BNODES];
    __shared__ int cursor[BNODES];
    __shared__ int sbase[MAXBUCK];
    __shared__ int wsum[4];
    __shared__ int w2[2];
    __shared__ unsigned short staging[P4CAP];
    const int b = blockIdx.x, tid = threadIdx.x, lane = tid & 63, wid = tid >> 6;

    scan_totals2(totals, sbase, wsum, nbuck, tid);
    __syncthreads();
    const int gbase = sbase[b];
    const int cnt = totals[b];

    if (tid < BNODES) counts[tid] = 0;
    __syncthreads();
    for (int i = tid; i < cnt; i += 256)
        atomicAdd(&counts[ebuf[gbase + i] >> 16], 1);
    __syncthreads();

    // exclusive scan of BNODES=128 counts (first 2 waves)
    int c = 0, s = 0;
    if (tid < BNODES) {
        c = counts[tid];
        s = c;
#pragma unroll
        for (int off = 1; off < 64; off <<= 1) {
            int t = __shfl_up(s, off, 64);
            if (lane >= off) s += t;
        }
        if (lane == 63) w2[wid] = s;
    }
    __syncthreads();
    if (tid == 0) { int t = w2[0]; w2[0] = 0; w2[1] = t; }
    __syncthreads();
    if (tid < BNODES) {
        int excl = w2[wid] + s - c;
        cursor[tid] = excl;
        int node = b * BNODES + tid;
        if (node < N) {
            rowptr[node] = gbase + excl;
            dis[node] = rsqrtf(1.0f + (float)c);
        }
    }
    if (b == 0 && tid == 0) rowptr[N] = E;
    __syncthreads();

    if (cnt <= P4CAP) {
        for (int i = tid; i < cnt; i += 256) {
            unsigned v = ebuf[gbase + i];
            int pos = atomicAdd(&cursor[v >> 16], 1);
            staging[pos] = (unsigned short)(v & 0xFFFFu);
        }
        __syncthreads();
        for (int i = tid; i < cnt; i += 256)
            csr[gbase + i] = staging[i];
    } else {
        for (int i = tid; i < cnt; i += 256) {
            unsigned v = ebuf[gbase + i];
            int pos = atomicAdd(&cursor[v >> 16], 1);
            csr[gbase + pos] = (unsigned short)(v & 0xFFFFu);
        }
    }

    // ---- fused xconv for this bucket's nodes (uses counts[] for dis) ----
    const int nloc = min(BNODES, N - b * BNODES);   // nodes in this bucket
    if (nloc > 0) {
        const int tot = nloc * (KP1 / 2);
        for (int i = tid; i < tot; i += 256) {
            int nl = i / (KP1 / 2), cc = i % (KP1 / 2);
            int node = b * BNODES + nl;
            float d = rsqrtf(1.0f + (float)counts[nl]);
            const float* xr = X + (size_t)node * KIN;
            float a = (2 * cc     < KIN) ? d * xr[2 * cc]     : 0.0f;
            float bb = (2 * cc + 1 < KIN) ? d * xr[2 * cc + 1] : 0.0f;
            Xhs[(size_t)node * (KP1 / 2) + cc] = pack_bf16(a, bb);
        }
    }
}

// ---- fused: gather 16 nodes -> LDS (bf16), then MFMA GEMM from LDS ----
// Gather: one pass, 4 waves x 4 nodes/wave; 16-lane group per node, lane
// sl reads row chunk min(sl, ROWU4-1) (dup lanes touch no extra lines);
// 4 independent csr->row chains per wave.
// GEMM: 4 waves share the block's 16 rows (B-frag from LDS); wave w
// computes col tiles {2w, 2w+1} (A-frag = weights from global, L1/L2-hot).
//   LAYER1: store bf16( relu(d*acc + b) * d )   (pre-scaled rows for layer 2)
//   LAYER2: store fp32( relu(d*acc + b) )
template<int KPA, bool LAYER1>
__global__ __launch_bounds__(256) void fused_kernel(
    const uint4* __restrict__ rows, const int* __restrict__ rowptr,
    const unsigned short* __restrict__ csr,
    const unsigned short* __restrict__ Wt, const float* __restrict__ bias,
    const float* __restrict__ dis, void* __restrict__ outp, int N)
{
    constexpr int ROWU4 = KPA / 8;                 // uint4 chunks per row
    constexpr int LDSP  = (KPA == 96) ? 104 : 136; // row stride (ushorts)
    __shared__ unsigned short lds_a[16][LDSP];
    const int tid  = threadIdx.x;
    const int wave = tid >> 6;
    const int lane = tid & 63;
    const int sub  = (lane >> 4) & 3;    // node slot within wave (0..3)
    const int sl   = lane & 15;          // 16B chunk within row
    const int slc  = (ROWU4 == 16) ? sl : min(sl, ROWU4 - 1);
    const bool act = (ROWU4 == 16) || (sl < ROWU4);
    const int blk0 = blockIdx.x * 16;

    // ---- gather phase: wave w fills LDS rows w*4 .. w*4+3 ----
    {
        const int lrow = wave * 4 + sub;
        const int node = blk0 + lrow;
        const bool valid = node < N;
        const int cn = valid ? node : N - 1;

        // self row (added once)
        uint4 sv = rows[(size_t)cn * ROWU4 + slc];
        float a0, a1, a2, a3, a4, a5, a6, a7;
        {
            float2 q;
            q = unpack_bf16(sv.x); a0 = q.x; a1 = q.y;
            q = unpack_bf16(sv.y); a2 = q.x; a3 = q.y;
            q = unpack_bf16(sv.z); a4 = q.x; a5 = q.y;
            q = unpack_bf16(sv.w); a6 = q.x; a7 = q.y;
        }

        int beg = rowptr[cn];
        int end = valid ? rowptr[cn + 1] : beg;
        int j = beg;
        for (; j + 4 <= end; j += 4) {   // 4 rows in flight per chain
            int r0 = csr[j], r1 = csr[j + 1], r2 = csr[j + 2], r3 = csr[j + 3];
            uint4 v0 = rows[(size_t)r0 * ROWU4 + slc];
            uint4 v1 = rows[(size_t)r1 * ROWU4 + slc];
            uint4 v2 = rows[(size_t)r2 * ROWU4 + slc];
            uint4 v3 = rows[(size_t)r3 * ROWU4 + slc];
            float2 q;
            q = unpack_bf16(v0.x); a0 += q.x; a1 += q.y;
            q = unpack_bf16(v0.y); a2 += q.x; a3 += q.y;
            q = unpack_bf16(v0.z); a4 += q.x; a5 += q.y;
            q = unpack_bf16(v0.w); a6 += q.x; a7 += q.y;
            q = unpack_bf16(v1.x); a0 += q.x; a1 += q.y;
            q = unpack_bf16(v1.y); a2 += q.x; a3 += q.y;
            q = unpack_bf16(v1.z); a4 += q.x; a5 += q.y;
            q = unpack_bf16(v1.w); a6 += q.x; a7 += q.y;
            q = unpack_bf16(v2.x); a0 += q.x; a1 += q.y;
            q = unpack_bf16(v2.y); a2 += q.x; a3 += q.y;
            q = unpack_bf16(v2.z); a4 += q.x; a5 += q.y;
            q = unpack_bf16(v2.w); a6 += q.x; a7 += q.y;
            q = unpack_bf16(v3.x); a0 += q.x; a1 += q.y;
            q = unpack_bf16(v3.y); a2 += q.x; a3 += q.y;
            q = unpack_bf16(v3.z); a4 += q.x; a5 += q.y;
            q = unpack_bf16(v3.w); a6 += q.x; a7 += q.y;
        }
        for (; j < end; ++j) {
            int r = csr[j];
            uint4 v = rows[(size_t)r * ROWU4 + slc];
            float2 q;
            q = unpack_bf16(v.x); a0 += q.x; a1 += q.y;
            q = unpack_bf16(v.y); a2 += q.x; a3 += q.y;
            q = unpack_bf16(v.z); a4 += q.x; a5 += q.y;
            q = unpack_bf16(v.w); a6 += q.x; a7 += q.y;
        }

        if (act) {
            uint4 pk = make_uint4(pack_bf16(a0, a1), pack_bf16(a2, a3),
                                  pack_bf16(a4, a5), pack_bf16(a6, a7));
            *(uint4*)&lds_a[lrow][sl * 8] = pk;
        }
    }
    __syncthreads();

    // ---- gemm phase: wave w -> col tiles {2w, 2w+1} over the 16 rows ----
    const int m    = lane & 15;
    const int quad = lane >> 4;
    const int node = blk0 + m;

    f32x4 acc[2];
    acc[0] = (f32x4){0.0f, 0.0f, 0.0f, 0.0f};
    acc[1] = (f32x4){0.0f, 0.0f, 0.0f, 0.0f};

    const unsigned short* arp = &lds_a[m][0];

#pragma unroll
    for (int c = 0; c < KPA / 32; ++c) {
        const int k0 = c * 32 + quad * 8;
        bf16x8 nv = *(const bf16x8*)(arp + k0);                      // B-frag (LDS)
#pragma unroll
        for (int t2 = 0; t2 < 2; ++t2) {
            const int t = wave * 2 + t2;
            bf16x8 wv = *(const bf16x8*)(Wt + (size_t)(t * 16 + m) * KPA + k0);  // A-frag
            acc[t2] = __builtin_amdgcn_mfma_f32_16x16x32_bf16(wv, nv, acc[t2], 0, 0, 0);
        }
    }

    if (node < N) {
        const float dv = dis[node];
#pragma unroll
        for (int t2 = 0; t2 < 2; ++t2) {
            const int col0 = (wave * 2 + t2) * 16 + quad * 4;
            float4 bb = *(const float4*)&bias[col0];
            float r0 = fmaxf(fmaf(dv, acc[t2][0], bb.x), 0.0f);
            float r1 = fmaxf(fmaf(dv, acc[t2][1], bb.y), 0.0f);
            float r2 = fmaxf(fmaf(dv, acc[t2][2], bb.z), 0.0f);
            float r3 = fmaxf(fmaf(dv, acc[t2][3], bb.w), 0.0f);
            if (LAYER1) {
                uint2 u;
                u.x = pack_bf16(r0 * dv, r1 * dv);
                u.y = pack_bf16(r2 * dv, r3 * dv);
                *(uint2*)((unsigned short*)outp + (size_t)node * HID + col0) = u;
            } else {
                float4 r = make_float4(r0, r1, r2, r3);
                *(float4*)((float*)outp + (size_t)node * HID + col0) = r;
            }
        }
    }
}

// ---------------- launch ----------------

static inline char* wsal(char*& p, size_t n) {
    uintptr_t q = ((uintptr_t)p + 255) & ~(uintptr_t)255;
    char* r = (char*)q;
    p = r + n;
    return r;
}

extern "C" void kernel_launch(void* const* d_in, const int* in_sizes, int n_in,
                              void* d_out, int out_size, void* d_ws, size_t ws_size,
                              hipStream_t stream) {
    const float* x  = (const float*)d_in[0];
    const int*   ei = (const int*)d_in[1];
    const float* W1 = (const float*)d_in[2];
    const float* b1 = (const float*)d_in[3];
    const float* W2 = (const float*)d_in[4];
    const float* b2 = (const float*)d_in[5];

    const int N = in_sizes[0] / KIN;  // 50000  (< 65536 required)
    const int E = in_sizes[1] / 2;    // 800000
    const int nbuck = (N + BNODES - 1) >> BSH;   // 391 (<= MAXBUCK)

    float* out  = (float*)d_out;
    float* outH = out;                      // [N,128] final fp32 output
    float* outE = out + (size_t)N * HID;    // [2,E] edge_index as float

    char* ws = (char*)d_ws;
    int*            histG  = (int*)wsal(ws, (size_t)MAXBUCK * NPB * 4);
    int*            totals = (int*)wsal(ws, MAXBUCK * 4);
    int*            rowptr = (int*)wsal(ws, (size_t)(N + 1) * 4);
    float*          dis    = (float*)wsal(ws, (size_t)N * 4);
    unsigned*       ebuf   = (unsigned*)wsal(ws, (size_t)E * 4);
    unsigned short* csr    = (unsigned short*)wsal(ws, (size_t)E * 2);
    unsigned*       Xhs    = (unsigned*)wsal(ws, (size_t)N * (KP1 / 2) * 4);
    unsigned short* g2h    = (unsigned short*)wsal(ws, (size_t)N * HID * 2);
    unsigned short* W1t    = (unsigned short*)wsal(ws, (size_t)HID * KP1 * 2);
    unsigned short* W2t    = (unsigned short*)wsal(ws, (size_t)HID * HID * 2);

    p1_kernel<<<NPB, 256, 0, stream>>>(ei, histG, W1, W1t, W2, W2t, E, nbuck);
    p2a_kernel<<<nbuck, NPB, 0, stream>>>(histG, totals);
    p3_part_kernel<<<NPB, 256, 0, stream>>>(ei, histG, totals, ebuf, outE,
                                            E, nbuck);
    p4_sort_kernel<<<nbuck, 256, 0, stream>>>(ebuf, totals, csr, rowptr, dis,
                                              x, Xhs, N, E, nbuck);

    const int ngf = (N + 15) / 16;

    // Layer 1: fused gather+gemm  (Xhs [N][96] -> g2h [N][128])
    fused_kernel<KP1, true><<<ngf, 256, 0, stream>>>(
        (const uint4*)Xhs, rowptr, csr, W1t, b1, dis, g2h, N);

    // Layer 2: fused gather+gemm  (g2h [N][128] -> outH fp32)
    fused_kernel<KP2, false><<<ngf, 256, 0, stream>>>(
        (const uint4*)g2h, rowptr, csr, W2t, b2, dis, outH, N);
}